// Round 1
// baseline (149.505 us; speedup 1.0000x reference)
//
#include <hip/hip_runtime.h>

// RBF: out[b, n, 0] = exp(-||x[b] - c[n]||^2 / 0.04)
//      out[b, n, 1] = exp(-||x_delayed[b] - c[n]||^2 / 0.04)
// B = 2048, N = 8192, out = [B, N, 2] fp32 (128 MiB) -> write-BW bound.
//
// exp(-d/beta) = exp2(d * (-log2(e)/beta)); beta = 0.04
#define EXP2_SCALE (-36.06737602222409f)   // -log2(e) / 0.04

#ifndef RBF_N_HALF_SHIFT
#define RBF_N_HALF_SHIFT 12                // log2(N/2) = log2(4096)
#endif

__global__ __launch_bounds__(256) void rbf_kernel(
    const float2* __restrict__ x,        // [B] of float2
    const float2* __restrict__ xd,       // [B] of float2
    const float4* __restrict__ c4,       // [N/2] of float4 (two centres)
    float4* __restrict__ out,            // [B * N/2] of float4
    int total)                           // B * N/2
{
    const int stride = gridDim.x * blockDim.x;
    for (int idx = blockIdx.x * blockDim.x + threadIdx.x; idx < total; idx += stride) {
        const int b  = idx >> RBF_N_HALF_SHIFT;            // idx / (N/2)
        const int nn = idx & ((1 << RBF_N_HALF_SHIFT) - 1); // idx % (N/2)

        const float2 xb  = x[b];    // broadcast within wave -> L1 hit
        const float2 xdb = xd[b];
        const float4 cc  = c4[nn];  // centres n (cc.x, cc.y) and n+1 (cc.z, cc.w)

        float dx, dy;

        dx = xb.x  - cc.x;  dy = xb.y  - cc.y;
        const float d00 = dx * dx + dy * dy;   // x vs centre n
        dx = xdb.x - cc.x;  dy = xdb.y - cc.y;
        const float d01 = dx * dx + dy * dy;   // x_delayed vs centre n
        dx = xb.x  - cc.z;  dy = xb.y  - cc.w;
        const float d10 = dx * dx + dy * dy;   // x vs centre n+1
        dx = xdb.x - cc.z;  dy = xdb.y - cc.w;
        const float d11 = dx * dx + dy * dy;   // x_delayed vs centre n+1

        float4 o;
        o.x = __builtin_amdgcn_exp2f(d00 * EXP2_SCALE);
        o.y = __builtin_amdgcn_exp2f(d01 * EXP2_SCALE);
        o.z = __builtin_amdgcn_exp2f(d10 * EXP2_SCALE);
        o.w = __builtin_amdgcn_exp2f(d11 * EXP2_SCALE);

        out[idx] = o;   // 16B coalesced store, 4 contiguous floats of [B,N,2]
    }
}

extern "C" void kernel_launch(void* const* d_in, const int* in_sizes, int n_in,
                              void* d_out, int out_size, void* d_ws, size_t ws_size,
                              hipStream_t stream) {
    const float2* x  = (const float2*)d_in[0];   // [B,2] fp32
    const float2* xd = (const float2*)d_in[1];   // [B,2] fp32
    const float4* c4 = (const float4*)d_in[2];   // [N,2] fp32 viewed as [N/2] float4
    float4* out = (float4*)d_out;                // [B,N,2] fp32 viewed as float4

    const int B = in_sizes[0] / 2;               // 2048
    const int N = in_sizes[2] / 2;               // 8192
    const int total = B * (N / 2);               // 8,388,608 float4 work items

    const int block = 256;
    const int grid  = 2048;                      // 8 blocks/CU, grid-stride the rest

    rbf_kernel<<<grid, block, 0, stream>>>(x, xd, c4, out, total);
}

// Round 5
// 148.540 us; speedup vs baseline: 1.0065x; 1.0065x over previous
//
#include <hip/hip_runtime.h>

// RBF: out[b, n, 0] = exp(-||x[b] - c[n]||^2 / 0.04)
//      out[b, n, 1] = exp(-||x_delayed[b] - c[n]||^2 / 0.04)
// B = 2048, N = 8192, out = [B, N, 2] fp32 (128 MiB) -> write-BW bound.
//
// Structure: one block per b-row. x[b]/xd[b] are block-uniform -> scalar
// loads hoisted out of the loop; inner loop has zero loop-carried deps so
// 8x-unrolled load/exp/store chains keep the store stream deep.
//
// exp(-d/beta) = exp2(d * (-log2(e)/beta)); beta = 0.04
#define EXP2_SCALE (-36.06737602222409f)   // -log2(e) / 0.04

#define N_RBF      8192
#define NPAIR      (N_RBF / 2)             // 4096 float4 per b-row
#define BLOCK      256
#define ITERS      (NPAIR / BLOCK)         // 16

// Native vector type: __builtin_nontemporal_store rejects HIP_vector_type.
typedef float f32x4 __attribute__((ext_vector_type(4)));

__global__ __launch_bounds__(BLOCK) void rbf_kernel(
    const float2* __restrict__ x,        // [B]
    const float2* __restrict__ xd,       // [B]
    const f32x4* __restrict__ c4,        // [N/2] (two centres per f32x4)
    f32x4* __restrict__ out)             // [B * N/2]
{
    const int b = blockIdx.x;            // one b-row per block
    const float2 xb  = x[b];             // block-uniform -> s_load, once
    const float2 xdb = xd[b];
    const int t = threadIdx.x;
    f32x4* __restrict__ orow = out + (size_t)b * NPAIR;

    #pragma unroll 8
    for (int i = 0; i < ITERS; ++i) {
        const int nn = i * BLOCK + t;
        const f32x4 cc = c4[nn];         // coalesced 16B/lane, L2-resident

        float dx, dy;
        dx = xb.x  - cc.x;  dy = xb.y  - cc.y;  const float d00 = dx*dx + dy*dy;
        dx = xdb.x - cc.x;  dy = xdb.y - cc.y;  const float d01 = dx*dx + dy*dy;
        dx = xb.x  - cc.z;  dy = xb.y  - cc.w;  const float d10 = dx*dx + dy*dy;
        dx = xdb.x - cc.z;  dy = xdb.y - cc.w;  const float d11 = dx*dx + dy*dy;

        f32x4 o;
        o.x = __builtin_amdgcn_exp2f(d00 * EXP2_SCALE);
        o.y = __builtin_amdgcn_exp2f(d01 * EXP2_SCALE);
        o.z = __builtin_amdgcn_exp2f(d10 * EXP2_SCALE);
        o.w = __builtin_amdgcn_exp2f(d11 * EXP2_SCALE);

        // Output has no reuse and is 4x the L2 -> nontemporal.
        __builtin_nontemporal_store(o, &orow[nn]);
    }
}

extern "C" void kernel_launch(void* const* d_in, const int* in_sizes, int n_in,
                              void* d_out, int out_size, void* d_ws, size_t ws_size,
                              hipStream_t stream) {
    const float2* x  = (const float2*)d_in[0];   // [B,2] fp32
    const float2* xd = (const float2*)d_in[1];   // [B,2] fp32
    const f32x4* c4  = (const f32x4*)d_in[2];    // [N,2] fp32 as [N/2] f32x4
    f32x4* out = (f32x4*)d_out;                  // [B,N,2] fp32 as f32x4

    const int B = in_sizes[0] / 2;               // 2048

    rbf_kernel<<<B, BLOCK, 0, stream>>>(x, xd, c4, out);
}